// Round 17
// baseline (644.769 us; speedup 1.0000x reference)
//
#include <hip/hip_runtime.h>
#include <hip/hip_bf16.h>
#include <cstdint>
#include <cstddef>

#define N_NODES   100000
#define N_EDGES   1600000
#define N_GRAPHS  64
#define HIDDEN    256
#define N_CLASSES 10
#define NEG_SLOPE 0.01f

#define E_PAD    (N_EDGES + 8 * N_NODES)
#define N_RANGES 8
#define R_SIZE   ((N_NODES + N_RANGES - 1) / N_RANGES)   // 12500
#define CHUNK    2048
#define GEMM_BLOCKS 391   // 8 waves each, ~2 strips/wave, 2 blocks/CU (LDS-capped)
#define N32 ((size_t)N_NODES * 32)                        // bytes per feature-chunk region
#define AGG_BLOCKS (8 * (N_NODES / 32))                   // 8 chunks x 3125 node-blocks

typedef __attribute__((ext_vector_type(4))) float f32x4;    // MFMA C/D
typedef __attribute__((ext_vector_type(2))) float f32x2;

__device__ __forceinline__ float bf2f(unsigned short u) {
    return __uint_as_float(((unsigned int)u) << 16);
}

// pack one float -> fp8 e4m3 byte (HW cvt)
__device__ __forceinline__ unsigned char f2fp8(float v) {
    return (unsigned char)(__builtin_amdgcn_cvt_pk_fp8_f32(v, v, 0, false) & 0xff);
}

// ---------------- degree histogram: XCD-range-partitioned ----------------
__global__ __launch_bounds__(256) void k_deg_hist(const int* __restrict__ dst, int* __restrict__ cnt) {
    int b = blockIdx.x;
    int r = b & (N_RANGES - 1);
    int lo = r * R_SIZE, hi = lo + R_SIZE;
    int e0 = (b >> 3) * CHUNK + threadIdx.x * 8;
    if (e0 >= N_EDGES) return;
    int4 da = *(const int4*)(dst + e0);
    int4 db = *(const int4*)(dst + e0 + 4);
    int d[8] = {da.x, da.y, da.z, da.w, db.x, db.y, db.z, db.w};
#pragma unroll
    for (int j = 0; j < 8; ++j) {
        if (d[j] >= lo && d[j] < hi) atomicAdd(&cnt[d[j]], 1);
    }
}

// ---------------- graph boundaries via binary search (batch is sorted) ----------------
__global__ void k_graph_bounds(const int* __restrict__ batch,
                               int* __restrict__ gstart, int* __restrict__ gcnt) {
    int g = threadIdx.x;  // 0..63
    int lo = 0, hi = N_NODES;
    while (lo < hi) { int mid = (lo + hi) >> 1; if (batch[mid] < g) lo = mid + 1; else hi = mid; }
    __shared__ int sh[N_GRAPHS + 1];
    sh[g] = lo;
    if (g == 0) sh[N_GRAPHS] = N_NODES;
    __syncthreads();
    gstart[g] = sh[g];
    gcnt[g]   = sh[g + 1] - sh[g];
}

__global__ void k_dinv(const int* __restrict__ cnt, float* __restrict__ dinv) {
    int i = blockIdx.x * 256 + threadIdx.x;
    if (i < N_NODES) dinv[i] = rsqrtf((float)cnt[i] + 1.0f);
}

// ---------------- pad x [N,3] -> float4 [N] ----------------
__global__ void k_xpad(const float* __restrict__ x, float4* __restrict__ xp) {
    int i = blockIdx.x * 256 + threadIdx.x;
    if (i < N_NODES) xp[i] = make_float4(x[i * 3 + 0], x[i * 3 + 1], x[i * 3 + 2], 0.f);
}

// ---------------- exclusive scan of PADDED degree counts (CSR offsets) ----------------
__global__ void k_scanA(const int* __restrict__ cnt, int* __restrict__ out, int* __restrict__ bsum) {
    __shared__ int sh[256];
    int tid = threadIdx.x;
    int base = blockIdx.x * 1024 + tid * 4;
    int v[4]; int s = 0;
#pragma unroll
    for (int i = 0; i < 4; i++) {
        int idx = base + i;
        v[i] = (idx < N_NODES) ? ((cnt[idx] + 7) & ~7) : 0;
        s += v[i];
    }
    sh[tid] = s; __syncthreads();
    for (int off = 1; off < 256; off <<= 1) {
        int t = (tid >= off) ? sh[tid - off] : 0;
        __syncthreads();
        sh[tid] += t;
        __syncthreads();
    }
    int excl = sh[tid] - s;
    if (tid == 255) bsum[blockIdx.x] = sh[255];
#pragma unroll
    for (int i = 0; i < 4; i++) { int idx = base + i; if (idx < N_NODES) out[idx] = excl; excl += v[i]; }
}

__global__ void k_scanB(int* __restrict__ bsum, int nb) {
    __shared__ int sh[128];
    int tid = threadIdx.x;
    int v = (tid < nb) ? bsum[tid] : 0;
    sh[tid] = v; __syncthreads();
    for (int off = 1; off < 128; off <<= 1) {
        int t = (tid >= off) ? sh[tid - off] : 0;
        __syncthreads();
        sh[tid] += t;
        __syncthreads();
    }
    if (tid < nb) bsum[tid] = sh[tid] - v;  // exclusive
}

// finalize offsets + init cursor + final {0,0.0} records into padding slots
__global__ void k_scanC(int* __restrict__ off_arr, const int* __restrict__ bsum,
                        int* __restrict__ cursor, const int* __restrict__ cnt,
                        int2* __restrict__ rec) {
    int i = blockIdx.x * 256 + threadIdx.x;
    if (i < N_NODES) {
        int v = off_arr[i] + bsum[i >> 10];
        off_arr[i] = v;
        cursor[i]  = v;
        int c  = cnt[i];
        int cp = (c + 7) & ~7;
        for (int p = v + c; p < v + cp; ++p) rec[p] = make_int2(0, 0);
        if (i == N_NODES - 1) off_arr[N_NODES] = v + cp;
    }
}

// ---------------- XCD-partitioned CSR fill, coef fused ----------------
__global__ __launch_bounds__(256) void k_fill(const int* __restrict__ src, const int* __restrict__ dst,
                                              const float* __restrict__ dinv,
                                              int* __restrict__ cursor, int2* __restrict__ rec) {
    int b = blockIdx.x;
    int r = b & (N_RANGES - 1);
    int lo = r * R_SIZE, hi = lo + R_SIZE;
    int e0 = (b >> 3) * CHUNK + threadIdx.x * 8;
    if (e0 >= N_EDGES) return;
    int4 da = *(const int4*)(dst + e0);
    int4 db = *(const int4*)(dst + e0 + 4);
    int d[8] = {da.x, da.y, da.z, da.w, db.x, db.y, db.z, db.w};
#pragma unroll
    for (int j = 0; j < 8; ++j) {
        if (d[j] >= lo && d[j] < hi) {
            int s = src[e0 + j];
            float c = dinv[s] * dinv[d[j]];
            int p = atomicAdd(&cursor[d[j]], 1);
            rec[p] = make_int2(s, __float_as_int(c));
        }
    }
}

// ---------------- weight prep: W[k][n] fp32 -> fp8 in MFMA-fragment-swizzled order ----------------
__global__ void k_wprep(const float* __restrict__ W, unsigned char* __restrict__ Wswz) {
    int n = blockIdx.x; int k = threadIdx.x;  // 256 x 256
    unsigned char v = f2fp8(W[k * HIDDEN + n]);
    int k0 = k >> 5, nt = n >> 4;
    int lane = (((k >> 3) & 3) << 4) | (n & 15);
    int j = k & 7;
    Wswz[(size_t)(((k0 * 16) + nt) * 64 + lane) * 8 + j] = v;
}

// ---------------- layer-1 reassociated: ax = Norm * x  (3 features, exact) ----------------
__global__ void k_agg3(const float4* __restrict__ xp, const int* __restrict__ off,
                       const int2* __restrict__ rec, const float* __restrict__ dinv,
                       float4* __restrict__ ax) {
    int i = blockIdx.x * 256 + threadIdx.x;
    if (i >= N_NODES) return;
    float di = dinv[i];
    float selfc = di * di;
    float4 xi = xp[i];
    float a0 = xi.x * selfc, a1 = xi.y * selfc, a2 = xi.z * selfc;
    int e = off[i], e1 = off[i + 1];
    for (; e < e1; e += 4) {
        const int4* rp = (const int4*)(rec + e);
        int4 r01 = rp[0];
        int4 r23 = rp[1];
        float4 x0 = xp[r01.x], x1 = xp[r01.z], x2 = xp[r23.x], x3 = xp[r23.z];
        float c0 = __int_as_float(r01.y), c1 = __int_as_float(r01.w);
        float c2 = __int_as_float(r23.y), c3 = __int_as_float(r23.w);
        a0 += c0 * x0.x + c1 * x1.x + c2 * x2.x + c3 * x3.x;
        a1 += c0 * x0.y + c1 * x1.y + c2 * x2.y + c3 * x3.y;
        a2 += c0 * x0.z + c1 * x1.z + c2 * x2.z + c3 * x3.z;
    }
    ax[i] = make_float4(a0, a1, a2, 0.f);
}

// h1 = leaky(ax @ W1 + b1), fp8 CHUNK-MAJOR out: hc[(c>>5)*N32 + node*32 + (c&31)]
__global__ void k_l1(const float4* __restrict__ ax, const float* __restrict__ W1,
                     const float* __restrict__ b1, unsigned char* __restrict__ out) {
    int node = blockIdx.x; int c = threadIdx.x;
    float4 a = ax[node];
    float v = a.x * W1[c] + a.y * W1[HIDDEN + c] + a.z * W1[2 * HIDDEN + c] + b1[c];
    v = v >= 0.f ? v : NEG_SLOPE * v;
    out[(size_t)(c >> 5) * N32 + (size_t)node * 32 + (c & 31)] = f2fp8(v);
}

// ---------------- fp8 MFMA GEMM: W in LDS (one barrier); A and C CHUNK-MAJOR ----------------
// A load: chunk k0, row, bytes quad*8 (8B, rows 32B apart -> better coalescing than row-major).
// C store: global tile nt_g in [0,16): chunk nt_g>>1, byte (nt_g&1)*16 + r.
__global__ __launch_bounds__(512, 2) void k_gemm_mfma(const unsigned char* __restrict__ A,
                                                      const unsigned char* __restrict__ Wswz,
                                                      unsigned char* __restrict__ C, int M) {
    __shared__ long Bs[8192];  // 64 KB
    int tid = threadIdx.x;
    {
        const float4* gsrc = (const float4*)Wswz;
        float4* ldst = (float4*)Bs;
#pragma unroll
        for (int i = 0; i < 8; ++i) ldst[tid + 512 * i] = gsrc[tid + 512 * i];
    }
    __syncthreads();
    int lane = tid & 63, wv = tid >> 6;
    int quad = lane >> 4, r = lane & 15;
    int nstrips = M >> 4;  // 6250
    for (int s = blockIdx.x * 8 + wv; s < nstrips; s += gridDim.x * 8) {
        int m0 = s * 16;
        long af[8];
#pragma unroll
        for (int k0 = 0; k0 < 8; ++k0)
            af[k0] = *(const long*)(A + (size_t)k0 * N32 + (size_t)(m0 + r) * 32 + quad * 8);
#pragma unroll
        for (int half = 0; half < 2; ++half) {
            f32x4 acc[8];
#pragma unroll
            for (int i = 0; i < 8; i++) acc[i] = (f32x4){0.f, 0.f, 0.f, 0.f};
#pragma unroll
            for (int k0 = 0; k0 < 8; ++k0) {
#pragma unroll
                for (int nt = 0; nt < 8; ++nt) {
                    long b = Bs[(k0 * 16 + half * 8 + nt) * 64 + lane];
                    acc[nt] = __builtin_amdgcn_mfma_f32_16x16x32_fp8_fp8(af[k0], b, acc[nt], 0, 0, 0);
                }
            }
#pragma unroll
            for (int nt = 0; nt < 8; ++nt) {
                int nt_g = half * 8 + nt;
                unsigned char* cbase = C + (size_t)(nt_g >> 1) * N32 + (size_t)(nt_g & 1) * 16;
#pragma unroll
                for (int i = 0; i < 4; ++i) {
                    int row = m0 + quad * 4 + i;
                    cbase[(size_t)row * 32 + r] = f2fp8(acc[nt][i]);
                }
            }
        }
    }
}

// ---------------- chunked aggregation: block b -> chunk c=b&7 (XCD-affine) ----------------
// wave = 8 nodes x 8 lanes (4B/lane = 32 features fp8); gathers stay in the XCD's 3.2MB chunk.
// edge loop unrolled 4 (degrees padded to multiple of 8); output chunk-major (same chunk).
__global__ __launch_bounds__(256) void k_agg(const unsigned char* __restrict__ hc,
                                             const float* __restrict__ bias,
                                             const int* __restrict__ off, const int2* __restrict__ rec,
                                             const float* __restrict__ dinv,
                                             unsigned char* __restrict__ out) {
    int b = blockIdx.x;
    int c = b & 7;
    int node = (b >> 3) * 32 + (threadIdx.x >> 3);
    int sl = threadIdx.x & 7;
    if (node >= N_NODES) return;
    float di = dinv[node];
    float selfc = di * di;
    const unsigned char* base = hc + (size_t)c * N32;
    unsigned int hv = *(const unsigned int*)(base + (size_t)node * 32 + sl * 4);
    f32x2 hlo = __builtin_amdgcn_cvt_pk_f32_fp8(hv, false);
    f32x2 hhi = __builtin_amdgcn_cvt_pk_f32_fp8(hv, true);
    float4 bv = ((const float4*)bias)[c * 8 + sl];
    float4 acc = make_float4(bv.x + hlo.x * selfc, bv.y + hlo.y * selfc,
                             bv.z + hhi.x * selfc, bv.w + hhi.y * selfc);
    int e = off[node], e1 = off[node + 1];
    for (; e < e1; e += 4) {
        int2 r0 = rec[e + 0];
        int2 r1 = rec[e + 1];
        int2 r2 = rec[e + 2];
        int2 r3 = rec[e + 3];
        unsigned int w0 = *(const unsigned int*)(base + (size_t)r0.x * 32 + sl * 4);
        unsigned int w1 = *(const unsigned int*)(base + (size_t)r1.x * 32 + sl * 4);
        unsigned int w2 = *(const unsigned int*)(base + (size_t)r2.x * 32 + sl * 4);
        unsigned int w3 = *(const unsigned int*)(base + (size_t)r3.x * 32 + sl * 4);
        float c0 = __int_as_float(r0.y), c1 = __int_as_float(r1.y);
        float c2 = __int_as_float(r2.y), c3 = __int_as_float(r3.y);
        f32x2 l0 = __builtin_amdgcn_cvt_pk_f32_fp8(w0, false), g0 = __builtin_amdgcn_cvt_pk_f32_fp8(w0, true);
        f32x2 l1 = __builtin_amdgcn_cvt_pk_f32_fp8(w1, false), g1 = __builtin_amdgcn_cvt_pk_f32_fp8(w1, true);
        f32x2 l2 = __builtin_amdgcn_cvt_pk_f32_fp8(w2, false), g2 = __builtin_amdgcn_cvt_pk_f32_fp8(w2, true);
        f32x2 l3 = __builtin_amdgcn_cvt_pk_f32_fp8(w3, false), g3 = __builtin_amdgcn_cvt_pk_f32_fp8(w3, true);
        acc.x += c0 * l0.x + c1 * l1.x + c2 * l2.x + c3 * l3.x;
        acc.y += c0 * l0.y + c1 * l1.y + c2 * l2.y + c3 * l3.y;
        acc.z += c0 * g0.x + c1 * g1.x + c2 * g2.x + c3 * g3.x;
        acc.w += c0 * g0.y + c1 * g1.y + c2 * g2.y + c3 * g3.y;
    }
    acc.x = acc.x >= 0.f ? acc.x : NEG_SLOPE * acc.x;
    acc.y = acc.y >= 0.f ? acc.y : NEG_SLOPE * acc.y;
    acc.z = acc.z >= 0.f ? acc.z : NEG_SLOPE * acc.z;
    acc.w = acc.w >= 0.f ? acc.w : NEG_SLOPE * acc.w;
    unsigned int pk = __builtin_amdgcn_cvt_pk_fp8_f32(acc.x, acc.y, 0, false);
    pk = __builtin_amdgcn_cvt_pk_fp8_f32(acc.z, acc.w, pk, true);
    *(unsigned int*)(out + (size_t)c * N32 + (size_t)node * 32 + sl * 4) = pk;
}

// ---------------- global mean pool (partial sums + atomics), chunk-major fp8 input ----------------
__global__ void k_pool(const unsigned char* __restrict__ hc, const int* __restrict__ gstart,
                       const int* __restrict__ gcnt, float* __restrict__ pooled) {
    int g = blockIdx.x, chunk = blockIdx.y, t = threadIdx.x;
    int s = gstart[g], c = gcnt[g];
    int i0 = s + (int)(((long long)c * chunk) / 16);
    int i1 = s + (int)(((long long)c * (chunk + 1)) / 16);
    const unsigned char* base = hc + (size_t)(t >> 5) * N32 + (t & 31);
    float acc = 0.f;
    for (int i = i0; i < i1; ++i) {
        f32x2 v = __builtin_amdgcn_cvt_pk_f32_fp8((unsigned int)base[(size_t)i * 32], false);
        acc += v.x;
    }
    atomicAdd(&pooled[g * HIDDEN + t], acc);
}

// ---------------- classifier head + softmax (one wave per graph) ----------------
__global__ void k_head(const float* __restrict__ pooled, const int* __restrict__ gcnt,
                       const float* __restrict__ Wc, const float* __restrict__ bc,
                       float* __restrict__ out) {
    int g = blockIdx.x; int l = threadIdx.x;  // 64 threads
    float inv = 1.0f / fmaxf((float)gcnt[g], 1.0f);
    float p[4];
#pragma unroll
    for (int i = 0; i < 4; i++) p[i] = pooled[g * HIDDEN + l + i * 64] * inv;
    __shared__ float logits[N_CLASSES];
#pragma unroll
    for (int j = 0; j < N_CLASSES; j++) {
        float s = 0.f;
#pragma unroll
        for (int i = 0; i < 4; i++) s += p[i] * Wc[(l + i * 64) * N_CLASSES + j];
        for (int o = 32; o > 0; o >>= 1) s += __shfl_down(s, o, 64);
        if (l == 0) logits[j] = s + bc[j];
    }
    __syncthreads();
    if (l == 0) {
        float m = logits[0];
        for (int j = 1; j < N_CLASSES; j++) m = fmaxf(m, logits[j]);
        float e[N_CLASSES]; float sum = 0.f;
        for (int j = 0; j < N_CLASSES; j++) { e[j] = expf(logits[j] - m); sum += e[j]; }
        for (int j = 0; j < N_CLASSES; j++) out[g * N_CLASSES + j] = e[j] / sum;
    }
}

extern "C" void kernel_launch(void* const* d_in, const int* in_sizes, int n_in,
                              void* d_out, int out_size, void* d_ws, size_t ws_size,
                              hipStream_t stream) {
    const float* x     = (const float*)d_in[0];
    const int*   edge  = (const int*)d_in[1];
    const int*   batch = (const int*)d_in[2];
    const float* W1 = (const float*)d_in[3];
    const float* b1 = (const float*)d_in[4];
    const float* W2 = (const float*)d_in[5];
    const float* b2 = (const float*)d_in[6];
    const float* W3 = (const float*)d_in[7];
    const float* b3 = (const float*)d_in[8];
    const float* Wc = (const float*)d_in[9];
    const float* bc = (const float*)d_in[10];
    float* out = (float*)d_out;
    const int* srcp = edge;
    const int* dstp = edge + N_EDGES;

    char* ws = (char*)d_ws;
    size_t off = 0;
    auto alloc = [&](size_t bytes) -> char* {
        char* p = ws + off;
        off += (bytes + 255) & ~(size_t)255;
        return p;
    };
    unsigned char* hA   = (unsigned char*)alloc((size_t)N_NODES * HIDDEN);  // chunk-major fp8 (GEMM in)
    unsigned char* hB   = (unsigned char*)alloc((size_t)N_NODES * HIDDEN);  // chunk-major fp8 (gathered)
    unsigned char* Wz2  = (unsigned char*)alloc((size_t)HIDDEN * HIDDEN);
    unsigned char* Wz3  = (unsigned char*)alloc((size_t)HIDDEN * HIDDEN);
    int*   deg_cnt  = (int*)alloc((size_t)N_NODES * 4);
    float* dinv     = (float*)alloc((size_t)N_NODES * 4);
    int*   csr_off  = (int*)alloc((size_t)(N_NODES + 1) * 4);
    int*   cursor   = (int*)alloc((size_t)N_NODES * 4);
    int2*  csr_rec  = (int2*)alloc((size_t)E_PAD * 8);
    float4* ax      = (float4*)alloc((size_t)N_NODES * 16);
    float4* xp      = (float4*)alloc((size_t)N_NODES * 16);
    int*   gcnt     = (int*)alloc((size_t)N_GRAPHS * 4);
    int*   gstart   = (int*)alloc((size_t)N_GRAPHS * 4);
    float* pooled   = (float*)alloc((size_t)N_GRAPHS * HIDDEN * 4);
    int*   bsum     = (int*)alloc(128 * 4);

    hipMemsetAsync(deg_cnt, 0, (size_t)N_NODES * 4, stream);
    hipMemsetAsync(pooled, 0, (size_t)N_GRAPHS * HIDDEN * 4, stream);

    int nb  = (N_NODES + 255) / 256;
    int sblocks = (N_NODES + 1023) / 1024;  // 98
    int fillb = N_RANGES * ((N_EDGES + CHUNK - 1) / CHUNK);  // 8 x 782

    k_deg_hist<<<fillb, 256, 0, stream>>>(dstp, deg_cnt);
    k_graph_bounds<<<1, 64, 0, stream>>>(batch, gstart, gcnt);
    k_dinv<<<nb, 256, 0, stream>>>(deg_cnt, dinv);
    k_xpad<<<nb, 256, 0, stream>>>(x, xp);
    k_scanA<<<sblocks, 256, 0, stream>>>(deg_cnt, csr_off, bsum);
    k_scanB<<<1, 128, 0, stream>>>(bsum, sblocks);
    k_scanC<<<nb, 256, 0, stream>>>(csr_off, bsum, cursor, deg_cnt, csr_rec);
    k_fill<<<fillb, 256, 0, stream>>>(srcp, dstp, dinv, cursor, csr_rec);
    k_wprep<<<HIDDEN, HIDDEN, 0, stream>>>(W2, Wz2);
    k_wprep<<<HIDDEN, HIDDEN, 0, stream>>>(W3, Wz3);

    // layer 1 (reassociated): ax = Norm*x; h1 = leaky(ax @ W1 + b1) -> hA (chunk-major fp8)
    k_agg3<<<nb, 256, 0, stream>>>(xp, csr_off, csr_rec, dinv, ax);
    k_l1<<<N_NODES, 256, 0, stream>>>(ax, W1, b1, hA);

    // layer 2
    k_gemm_mfma<<<GEMM_BLOCKS, 512, 0, stream>>>(hA, Wz2, hB, N_NODES);
    k_agg<<<AGG_BLOCKS, 256, 0, stream>>>(hB, b2, csr_off, csr_rec, dinv, hA);
    // layer 3
    k_gemm_mfma<<<GEMM_BLOCKS, 512, 0, stream>>>(hA, Wz3, hB, N_NODES);
    k_agg<<<AGG_BLOCKS, 256, 0, stream>>>(hB, b3, csr_off, csr_rec, dinv, hA);
    // pool + head
    dim3 pg(N_GRAPHS, 16);
    k_pool<<<pg, 256, 0, stream>>>(hA, gstart, gcnt, pooled);
    k_head<<<N_GRAPHS, 64, 0, stream>>>(pooled, gcnt, Wc, bc, out);
}

// Round 18
// 559.516 us; speedup vs baseline: 1.1524x; 1.1524x over previous
//
#include <hip/hip_runtime.h>
#include <hip/hip_bf16.h>
#include <cstdint>
#include <cstddef>

#define N_NODES   100000
#define N_EDGES   1600000
#define N_GRAPHS  64
#define HIDDEN    256
#define N_CLASSES 10
#define NEG_SLOPE 0.01f

#define E_PAD    (N_EDGES + 8 * N_NODES)
#define N_RANGES 8
#define R_SIZE   ((N_NODES + N_RANGES - 1) / N_RANGES)   // 12500
#define CHUNK    2048
#define GEMM_BLOCKS 391   // 8 waves each, ~2 strips/wave, 2 blocks/CU (LDS-capped)

typedef __attribute__((ext_vector_type(4))) float f32x4;    // MFMA C/D
typedef __attribute__((ext_vector_type(2))) float f32x2;

__device__ __forceinline__ float bf2f(unsigned short u) {
    return __uint_as_float(((unsigned int)u) << 16);
}

// pack one float -> fp8 e4m3 byte (HW cvt)
__device__ __forceinline__ unsigned char f2fp8(float v) {
    return (unsigned char)(__builtin_amdgcn_cvt_pk_fp8_f32(v, v, 0, false) & 0xff);
}

// ---------------- degree histogram: XCD-range-partitioned ----------------
__global__ __launch_bounds__(256) void k_deg_hist(const int* __restrict__ dst, int* __restrict__ cnt) {
    int b = blockIdx.x;
    int r = b & (N_RANGES - 1);
    int lo = r * R_SIZE, hi = lo + R_SIZE;
    int e0 = (b >> 3) * CHUNK + threadIdx.x * 8;
    if (e0 >= N_EDGES) return;
    int4 da = *(const int4*)(dst + e0);
    int4 db = *(const int4*)(dst + e0 + 4);
    int d[8] = {da.x, da.y, da.z, da.w, db.x, db.y, db.z, db.w};
#pragma unroll
    for (int j = 0; j < 8; ++j) {
        if (d[j] >= lo && d[j] < hi) atomicAdd(&cnt[d[j]], 1);
    }
}

// ---------------- graph boundaries via binary search (batch is sorted) ----------------
__global__ void k_graph_bounds(const int* __restrict__ batch,
                               int* __restrict__ gstart, int* __restrict__ gcnt) {
    int g = threadIdx.x;  // 0..63
    int lo = 0, hi = N_NODES;
    while (lo < hi) { int mid = (lo + hi) >> 1; if (batch[mid] < g) lo = mid + 1; else hi = mid; }
    __shared__ int sh[N_GRAPHS + 1];
    sh[g] = lo;
    if (g == 0) sh[N_GRAPHS] = N_NODES;
    __syncthreads();
    gstart[g] = sh[g];
    gcnt[g]   = sh[g + 1] - sh[g];
}

// ---------------- fused: dinv + x padding ----------------
__global__ void k_dinv_xpad(const int* __restrict__ cnt, const float* __restrict__ x,
                            float* __restrict__ dinv, float4* __restrict__ xp) {
    int i = blockIdx.x * 256 + threadIdx.x;
    if (i < N_NODES) {
        dinv[i] = rsqrtf((float)cnt[i] + 1.0f);
        xp[i] = make_float4(x[i * 3 + 0], x[i * 3 + 1], x[i * 3 + 2], 0.f);
    }
}

// ---------------- exclusive scan of PADDED degree counts (CSR offsets) ----------------
__global__ void k_scanA(const int* __restrict__ cnt, int* __restrict__ out, int* __restrict__ bsum) {
    __shared__ int sh[256];
    int tid = threadIdx.x;
    int base = blockIdx.x * 1024 + tid * 4;
    int v[4]; int s = 0;
#pragma unroll
    for (int i = 0; i < 4; i++) {
        int idx = base + i;
        v[i] = (idx < N_NODES) ? ((cnt[idx] + 7) & ~7) : 0;
        s += v[i];
    }
    sh[tid] = s; __syncthreads();
    for (int off = 1; off < 256; off <<= 1) {
        int t = (tid >= off) ? sh[tid - off] : 0;
        __syncthreads();
        sh[tid] += t;
        __syncthreads();
    }
    int excl = sh[tid] - s;
    if (tid == 255) bsum[blockIdx.x] = sh[255];
#pragma unroll
    for (int i = 0; i < 4; i++) { int idx = base + i; if (idx < N_NODES) out[idx] = excl; excl += v[i]; }
}

__global__ void k_scanB(int* __restrict__ bsum, int nb) {
    __shared__ int sh[128];
    int tid = threadIdx.x;
    int v = (tid < nb) ? bsum[tid] : 0;
    sh[tid] = v; __syncthreads();
    for (int off = 1; off < 128; off <<= 1) {
        int t = (tid >= off) ? sh[tid - off] : 0;
        __syncthreads();
        sh[tid] += t;
        __syncthreads();
    }
    if (tid < nb) bsum[tid] = sh[tid] - v;  // exclusive
}

// finalize offsets + init cursor + final {0,0.0} records into padding slots
__global__ void k_scanC(int* __restrict__ off_arr, const int* __restrict__ bsum,
                        int* __restrict__ cursor, const int* __restrict__ cnt,
                        int2* __restrict__ rec) {
    int i = blockIdx.x * 256 + threadIdx.x;
    if (i < N_NODES) {
        int v = off_arr[i] + bsum[i >> 10];
        off_arr[i] = v;
        cursor[i]  = v;
        int c  = cnt[i];
        int cp = (c + 7) & ~7;
        for (int p = v + c; p < v + cp; ++p) rec[p] = make_int2(0, 0);
        if (i == N_NODES - 1) off_arr[N_NODES] = v + cp;
    }
}

// ---------------- XCD-partitioned CSR fill, coef fused ----------------
__global__ __launch_bounds__(256) void k_fill(const int* __restrict__ src, const int* __restrict__ dst,
                                              const float* __restrict__ dinv,
                                              int* __restrict__ cursor, int2* __restrict__ rec) {
    int b = blockIdx.x;
    int r = b & (N_RANGES - 1);
    int lo = r * R_SIZE, hi = lo + R_SIZE;
    int e0 = (b >> 3) * CHUNK + threadIdx.x * 8;
    if (e0 >= N_EDGES) return;
    int4 da = *(const int4*)(dst + e0);
    int4 db = *(const int4*)(dst + e0 + 4);
    int d[8] = {da.x, da.y, da.z, da.w, db.x, db.y, db.z, db.w};
#pragma unroll
    for (int j = 0; j < 8; ++j) {
        if (d[j] >= lo && d[j] < hi) {
            int s = src[e0 + j];
            float c = dinv[s] * dinv[d[j]];
            int p = atomicAdd(&cursor[d[j]], 1);
            rec[p] = make_int2(s, __float_as_int(c));
        }
    }
}

// ---------------- weight prep: W[k][n] fp32 -> fp8 in MFMA-fragment-swizzled order ----------------
__global__ void k_wprep(const float* __restrict__ W, unsigned char* __restrict__ Wswz) {
    int n = blockIdx.x; int k = threadIdx.x;  // 256 x 256
    unsigned char v = f2fp8(W[k * HIDDEN + n]);
    int k0 = k >> 5, nt = n >> 4;
    int lane = (((k >> 3) & 3) << 4) | (n & 15);
    int j = k & 7;
    Wswz[(size_t)(((k0 * 16) + nt) * 64 + lane) * 8 + j] = v;
}

// ---------------- layer-1 reassociated: ax = Norm * x  (3 features, exact) ----------------
__global__ void k_agg3(const float4* __restrict__ xp, const int* __restrict__ off,
                       const int2* __restrict__ rec, const float* __restrict__ dinv,
                       float4* __restrict__ ax) {
    int i = blockIdx.x * 256 + threadIdx.x;
    if (i >= N_NODES) return;
    float di = dinv[i];
    float selfc = di * di;
    float4 xi = xp[i];
    float a0 = xi.x * selfc, a1 = xi.y * selfc, a2 = xi.z * selfc;
    int e = off[i], e1 = off[i + 1];
    for (; e < e1; e += 4) {
        const int4* rp = (const int4*)(rec + e);
        int4 r01 = rp[0];
        int4 r23 = rp[1];
        float4 x0 = xp[r01.x], x1 = xp[r01.z], x2 = xp[r23.x], x3 = xp[r23.z];
        float c0 = __int_as_float(r01.y), c1 = __int_as_float(r01.w);
        float c2 = __int_as_float(r23.y), c3 = __int_as_float(r23.w);
        a0 += c0 * x0.x + c1 * x1.x + c2 * x2.x + c3 * x3.x;
        a1 += c0 * x0.y + c1 * x1.y + c2 * x2.y + c3 * x3.y;
        a2 += c0 * x0.z + c1 * x1.z + c2 * x2.z + c3 * x3.z;
    }
    ax[i] = make_float4(a0, a1, a2, 0.f);
}

// h1 = leaky(ax @ W1 + b1), fp8 out (hA row-major, linear-read by GEMM)
__global__ void k_l1(const float4* __restrict__ ax, const float* __restrict__ W1,
                     const float* __restrict__ b1, unsigned char* __restrict__ out) {
    int node = blockIdx.x; int c = threadIdx.x;
    float4 a = ax[node];
    float v = a.x * W1[c] + a.y * W1[HIDDEN + c] + a.z * W1[2 * HIDDEN + c] + b1[c];
    v = v >= 0.f ? v : NEG_SLOPE * v;
    out[(size_t)node * HIDDEN + c] = f2fp8(v);
}

// ---------------- fp8 MFMA GEMM: whole W (64 KB fp8, pre-swizzled) in LDS, ONE barrier ----------------
__global__ __launch_bounds__(512, 2) void k_gemm_mfma(const unsigned char* __restrict__ A,
                                                      const unsigned char* __restrict__ Wswz,
                                                      unsigned char* __restrict__ C, int M) {
    __shared__ long Bs[8192];  // 64 KB
    int tid = threadIdx.x;
    {
        const float4* gsrc = (const float4*)Wswz;
        float4* ldst = (float4*)Bs;
#pragma unroll
        for (int i = 0; i < 8; ++i) ldst[tid + 512 * i] = gsrc[tid + 512 * i];
    }
    __syncthreads();
    int lane = tid & 63, wv = tid >> 6;
    int quad = lane >> 4, r = lane & 15;
    int nstrips = M >> 4;  // 6250
    for (int s = blockIdx.x * 8 + wv; s < nstrips; s += gridDim.x * 8) {
        int m0 = s * 16;
        const long* Ab = (const long*)(A + (size_t)(m0 + r) * HIDDEN) + quad;
        long af[8];
#pragma unroll
        for (int k0 = 0; k0 < 8; ++k0) af[k0] = Ab[k0 * 4];
#pragma unroll
        for (int half = 0; half < 2; ++half) {
            f32x4 acc[8];
#pragma unroll
            for (int i = 0; i < 8; i++) acc[i] = (f32x4){0.f, 0.f, 0.f, 0.f};
#pragma unroll
            for (int k0 = 0; k0 < 8; ++k0) {
#pragma unroll
                for (int nt = 0; nt < 8; ++nt) {
                    long b = Bs[(k0 * 16 + half * 8 + nt) * 64 + lane];
                    acc[nt] = __builtin_amdgcn_mfma_f32_16x16x32_fp8_fp8(af[k0], b, acc[nt], 0, 0, 0);
                }
            }
#pragma unroll
            for (int nt = 0; nt < 8; ++nt) {
#pragma unroll
                for (int i = 0; i < 4; ++i) {
                    int row = m0 + quad * 4 + i;
                    C[(size_t)row * HIDDEN + (half * 8 + nt) * 16 + r] = f2fp8(acc[nt][i]);
                }
            }
        }
    }
}

// ---------------- fused aggregation + self-loop + bias + leaky-relu ----------------
// one wave per node; h rows fp8 (256 B); 8 gathers in flight; rec records PREFETCHED
// one iteration ahead (explicit 2-stage pipeline to hide rec-load -> gather-addr latency)
__global__ __launch_bounds__(256) void k_agg(const unsigned char* __restrict__ h,
                                             const float* __restrict__ bias,
                                             const int* __restrict__ off, const int2* __restrict__ rec,
                                             const float* __restrict__ dinv,
                                             unsigned char* __restrict__ out) {
    int node = (blockIdx.x * 256 + threadIdx.x) >> 6;
    int lane = threadIdx.x & 63;
    if (node >= N_NODES) return;
    float di = dinv[node];
    float selfc = di * di;
    unsigned int hv = *(const unsigned int*)(h + (size_t)node * HIDDEN + lane * 4);
    f32x2 hlo = __builtin_amdgcn_cvt_pk_f32_fp8(hv, false);
    f32x2 hhi = __builtin_amdgcn_cvt_pk_f32_fp8(hv, true);
    float4 bv = ((const float4*)bias)[lane];
    float4 acc = make_float4(bv.x + hlo.x * selfc, bv.y + hlo.y * selfc,
                             bv.z + hhi.x * selfc, bv.w + hhi.y * selfc);
    int e = off[node], e1 = off[node + 1];
    if (e < e1) {
        const int4* rp = (const int4*)(rec + e);
        int4 ra = rp[0], rb = rp[1], rc = rp[2], rd = rp[3];
        for (;;) {
            int e2 = e + 8;
            bool more = e2 < e1;
            int4 na, nb, nc, nd;
            if (more) {
                const int4* rp2 = (const int4*)(rec + e2);
                na = rp2[0]; nb = rp2[1]; nc = rp2[2]; nd = rp2[3];
            }
            unsigned int w0 = *(const unsigned int*)(h + (size_t)ra.x * HIDDEN + lane * 4);
            unsigned int w1 = *(const unsigned int*)(h + (size_t)ra.z * HIDDEN + lane * 4);
            unsigned int w2 = *(const unsigned int*)(h + (size_t)rb.x * HIDDEN + lane * 4);
            unsigned int w3 = *(const unsigned int*)(h + (size_t)rb.z * HIDDEN + lane * 4);
            unsigned int w4 = *(const unsigned int*)(h + (size_t)rc.x * HIDDEN + lane * 4);
            unsigned int w5 = *(const unsigned int*)(h + (size_t)rc.z * HIDDEN + lane * 4);
            unsigned int w6 = *(const unsigned int*)(h + (size_t)rd.x * HIDDEN + lane * 4);
            unsigned int w7 = *(const unsigned int*)(h + (size_t)rd.z * HIDDEN + lane * 4);
            float c0 = __int_as_float(ra.y), c1 = __int_as_float(ra.w);
            float c2 = __int_as_float(rb.y), c3 = __int_as_float(rb.w);
            float c4 = __int_as_float(rc.y), c5 = __int_as_float(rc.w);
            float c6 = __int_as_float(rd.y), c7 = __int_as_float(rd.w);
            f32x2 l0 = __builtin_amdgcn_cvt_pk_f32_fp8(w0, false), g0 = __builtin_amdgcn_cvt_pk_f32_fp8(w0, true);
            f32x2 l1 = __builtin_amdgcn_cvt_pk_f32_fp8(w1, false), g1 = __builtin_amdgcn_cvt_pk_f32_fp8(w1, true);
            f32x2 l2 = __builtin_amdgcn_cvt_pk_f32_fp8(w2, false), g2 = __builtin_amdgcn_cvt_pk_f32_fp8(w2, true);
            f32x2 l3 = __builtin_amdgcn_cvt_pk_f32_fp8(w3, false), g3 = __builtin_amdgcn_cvt_pk_f32_fp8(w3, true);
            f32x2 l4 = __builtin_amdgcn_cvt_pk_f32_fp8(w4, false), g4 = __builtin_amdgcn_cvt_pk_f32_fp8(w4, true);
            f32x2 l5 = __builtin_amdgcn_cvt_pk_f32_fp8(w5, false), g5 = __builtin_amdgcn_cvt_pk_f32_fp8(w5, true);
            f32x2 l6 = __builtin_amdgcn_cvt_pk_f32_fp8(w6, false), g6 = __builtin_amdgcn_cvt_pk_f32_fp8(w6, true);
            f32x2 l7 = __builtin_amdgcn_cvt_pk_f32_fp8(w7, false), g7 = __builtin_amdgcn_cvt_pk_f32_fp8(w7, true);
            acc.x += c0 * l0.x + c1 * l1.x + c2 * l2.x + c3 * l3.x
                   + c4 * l4.x + c5 * l5.x + c6 * l6.x + c7 * l7.x;
            acc.y += c0 * l0.y + c1 * l1.y + c2 * l2.y + c3 * l3.y
                   + c4 * l4.y + c5 * l5.y + c6 * l6.y + c7 * l7.y;
            acc.z += c0 * g0.x + c1 * g1.x + c2 * g2.x + c3 * g3.x
                   + c4 * g4.x + c5 * g5.x + c6 * g6.x + c7 * g7.x;
            acc.w += c0 * g0.y + c1 * g1.y + c2 * g2.y + c3 * g3.y
                   + c4 * g4.y + c5 * g5.y + c6 * g6.y + c7 * g7.y;
            if (!more) break;
            ra = na; rb = nb; rc = nc; rd = nd;
            e = e2;
        }
    }
    acc.x = acc.x >= 0.f ? acc.x : NEG_SLOPE * acc.x;
    acc.y = acc.y >= 0.f ? acc.y : NEG_SLOPE * acc.y;
    acc.z = acc.z >= 0.f ? acc.z : NEG_SLOPE * acc.z;
    acc.w = acc.w >= 0.f ? acc.w : NEG_SLOPE * acc.w;
    unsigned int pk = __builtin_amdgcn_cvt_pk_fp8_f32(acc.x, acc.y, 0, false);
    pk = __builtin_amdgcn_cvt_pk_fp8_f32(acc.z, acc.w, pk, true);
    *(unsigned int*)(out + (size_t)node * HIDDEN + lane * 4) = pk;
}

// ---------------- global mean pool (partial sums + atomics), fp8 input ----------------
__global__ void k_pool(const unsigned char* __restrict__ h, const int* __restrict__ gstart,
                       const int* __restrict__ gcnt, float* __restrict__ pooled) {
    int g = blockIdx.x, chunk = blockIdx.y, t = threadIdx.x;
    int s = gstart[g], c = gcnt[g];
    int i0 = s + (int)(((long long)c * chunk) / 16);
    int i1 = s + (int)(((long long)c * (chunk + 1)) / 16);
    float acc = 0.f;
    for (int i = i0; i < i1; ++i) {
        f32x2 v = __builtin_amdgcn_cvt_pk_f32_fp8((unsigned int)h[(size_t)i * HIDDEN + t], false);
        acc += v.x;
    }
    atomicAdd(&pooled[g * HIDDEN + t], acc);
}

// ---------------- classifier head + softmax (one wave per graph) ----------------
__global__ void k_head(const float* __restrict__ pooled, const int* __restrict__ gcnt,
                       const float* __restrict__ Wc, const float* __restrict__ bc,
                       float* __restrict__ out) {
    int g = blockIdx.x; int l = threadIdx.x;  // 64 threads
    float inv = 1.0f / fmaxf((float)gcnt[g], 1.0f);
    float p[4];
#pragma unroll
    for (int i = 0; i < 4; i++) p[i] = pooled[g * HIDDEN + l + i * 64] * inv;
    __shared__ float logits[N_CLASSES];
#pragma unroll
    for (int j = 0; j < N_CLASSES; j++) {
        float s = 0.f;
#pragma unroll
        for (int i = 0; i < 4; i++) s += p[i] * Wc[(l + i * 64) * N_CLASSES + j];
        for (int o = 32; o > 0; o >>= 1) s += __shfl_down(s, o, 64);
        if (l == 0) logits[j] = s + bc[j];
    }
    __syncthreads();
    if (l == 0) {
        float m = logits[0];
        for (int j = 1; j < N_CLASSES; j++) m = fmaxf(m, logits[j]);
        float e[N_CLASSES]; float sum = 0.f;
        for (int j = 0; j < N_CLASSES; j++) { e[j] = expf(logits[j] - m); sum += e[j]; }
        for (int j = 0; j < N_CLASSES; j++) out[g * N_CLASSES + j] = e[j] / sum;
    }
}

extern "C" void kernel_launch(void* const* d_in, const int* in_sizes, int n_in,
                              void* d_out, int out_size, void* d_ws, size_t ws_size,
                              hipStream_t stream) {
    const float* x     = (const float*)d_in[0];
    const int*   edge  = (const int*)d_in[1];
    const int*   batch = (const int*)d_in[2];
    const float* W1 = (const float*)d_in[3];
    const float* b1 = (const float*)d_in[4];
    const float* W2 = (const float*)d_in[5];
    const float* b2 = (const float*)d_in[6];
    const float* W3 = (const float*)d_in[7];
    const float* b3 = (const float*)d_in[8];
    const float* Wc = (const float*)d_in[9];
    const float* bc = (const float*)d_in[10];
    float* out = (float*)d_out;
    const int* srcp = edge;
    const int* dstp = edge + N_EDGES;

    char* ws = (char*)d_ws;
    size_t off = 0;
    auto alloc = [&](size_t bytes) -> char* {
        char* p = ws + off;
        off += (bytes + 255) & ~(size_t)255;
        return p;
    };
    unsigned char* hA   = (unsigned char*)alloc((size_t)N_NODES * HIDDEN);  // row-major fp8 (GEMM in)
    unsigned char* hB   = (unsigned char*)alloc((size_t)N_NODES * HIDDEN);  // row-major fp8 (gathered)
    unsigned char* Wz2  = (unsigned char*)alloc((size_t)HIDDEN * HIDDEN);
    unsigned char* Wz3  = (unsigned char*)alloc((size_t)HIDDEN * HIDDEN);
    int*   deg_cnt  = (int*)alloc((size_t)N_NODES * 4);
    float* dinv     = (float*)alloc((size_t)N_NODES * 4);
    int*   csr_off  = (int*)alloc((size_t)(N_NODES + 1) * 4);
    int*   cursor   = (int*)alloc((size_t)N_NODES * 4);
    int2*  csr_rec  = (int2*)alloc((size_t)E_PAD * 8);
    float4* ax      = (float4*)alloc((size_t)N_NODES * 16);
    float4* xp      = (float4*)alloc((size_t)N_NODES * 16);
    int*   gcnt     = (int*)alloc((size_t)N_GRAPHS * 4);
    int*   gstart   = (int*)alloc((size_t)N_GRAPHS * 4);
    float* pooled   = (float*)alloc((size_t)N_GRAPHS * HIDDEN * 4);
    int*   bsum     = (int*)alloc(128 * 4);

    hipMemsetAsync(deg_cnt, 0, (size_t)N_NODES * 4, stream);
    hipMemsetAsync(pooled, 0, (size_t)N_GRAPHS * HIDDEN * 4, stream);

    int nb  = (N_NODES + 255) / 256;
    int sblocks = (N_NODES + 1023) / 1024;  // 98
    int fillb = N_RANGES * ((N_EDGES + CHUNK - 1) / CHUNK);  // 8 x 782

    k_deg_hist<<<fillb, 256, 0, stream>>>(dstp, deg_cnt);
    k_graph_bounds<<<1, 64, 0, stream>>>(batch, gstart, gcnt);
    k_dinv_xpad<<<nb, 256, 0, stream>>>(deg_cnt, x, dinv, xp);
    k_scanA<<<sblocks, 256, 0, stream>>>(deg_cnt, csr_off, bsum);
    k_scanB<<<1, 128, 0, stream>>>(bsum, sblocks);
    k_scanC<<<nb, 256, 0, stream>>>(csr_off, bsum, cursor, deg_cnt, csr_rec);
    k_fill<<<fillb, 256, 0, stream>>>(srcp, dstp, dinv, cursor, csr_rec);
    k_wprep<<<HIDDEN, HIDDEN, 0, stream>>>(W2, Wz2);
    k_wprep<<<HIDDEN, HIDDEN, 0, stream>>>(W3, Wz3);

    // layer 1 (reassociated): ax = Norm*x; h1 = leaky(ax @ W1 + b1) -> hA (fp8)
    k_agg3<<<nb, 256, 0, stream>>>(xp, csr_off, csr_rec, dinv, ax);
    k_l1<<<N_NODES, 256, 0, stream>>>(ax, W1, b1, hA);

    int aggb = (N_NODES + 3) / 4;
    // layer 2
    k_gemm_mfma<<<GEMM_BLOCKS, 512, 0, stream>>>(hA, Wz2, hB, N_NODES);
    k_agg<<<aggb, 256, 0, stream>>>(hB, b2, csr_off, csr_rec, dinv, hA);
    // layer 3
    k_gemm_mfma<<<GEMM_BLOCKS, 512, 0, stream>>>(hA, Wz3, hB, N_NODES);
    k_agg<<<aggb, 256, 0, stream>>>(hB, b3, csr_off, csr_rec, dinv, hA);
    // pool + head
    dim3 pg(N_GRAPHS, 16);
    k_pool<<<pg, 256, 0, stream>>>(hA, gstart, gcnt, pooled);
    k_head<<<N_GRAPHS, 64, 0, stream>>>(pooled, gcnt, Wc, bc, out);
}

// Round 19
// 546.324 us; speedup vs baseline: 1.1802x; 1.0241x over previous
//
#include <hip/hip_runtime.h>
#include <hip/hip_bf16.h>
#include <hip/hip_fp16.h>
#include <cstdint>
#include <cstddef>

#define N_NODES   100000
#define N_EDGES   1600000
#define N_GRAPHS  64
#define HIDDEN    256
#define N_CLASSES 10
#define NEG_SLOPE 0.01f

#define E_PAD    (N_EDGES + 8 * N_NODES)
#define N_RANGES 8
#define R_SIZE   ((N_NODES + N_RANGES - 1) / N_RANGES)   // 12500
#define CHUNK    2048
#define GEMM_BLOCKS 391   // 8 waves each, ~2 strips/wave, 2 blocks/CU (LDS-capped)

typedef __attribute__((ext_vector_type(4))) float f32x4;    // MFMA C/D
typedef __attribute__((ext_vector_type(2))) float f32x2;

__device__ __forceinline__ float bf2f(unsigned short u) {
    return __uint_as_float(((unsigned int)u) << 16);
}

// pack one float -> fp8 e4m3 byte (HW cvt)
__device__ __forceinline__ unsigned char f2fp8(float v) {
    return (unsigned char)(__builtin_amdgcn_cvt_pk_fp8_f32(v, v, 0, false) & 0xff);
}

// ---- 4-byte edge record: src in bits [0,17), coef (positive fp16, sign stripped) in bits [17,32) ----
__device__ __forceinline__ unsigned int rec_pack(int s, float c) {
    __half h = __float2half(c);
    unsigned short hb = reinterpret_cast<const __half_raw*>(&h)->x;  // sign bit is 0 (c >= 0)
    return ((unsigned int)hb << 17) | (unsigned int)s;
}
__device__ __forceinline__ float rec_coef(unsigned int u) {
    __half_raw hr; hr.x = (unsigned short)(u >> 17);
    return __half2float(*reinterpret_cast<const __half*>(&hr));  // v_cvt_f32_f16, exact zero for u=0
}

// ---------------- degree histogram: XCD-range-partitioned ----------------
__global__ __launch_bounds__(256) void k_deg_hist(const int* __restrict__ dst, int* __restrict__ cnt) {
    int b = blockIdx.x;
    int r = b & (N_RANGES - 1);
    int lo = r * R_SIZE, hi = lo + R_SIZE;
    int e0 = (b >> 3) * CHUNK + threadIdx.x * 8;
    if (e0 >= N_EDGES) return;
    int4 da = *(const int4*)(dst + e0);
    int4 db = *(const int4*)(dst + e0 + 4);
    int d[8] = {da.x, da.y, da.z, da.w, db.x, db.y, db.z, db.w};
#pragma unroll
    for (int j = 0; j < 8; ++j) {
        if (d[j] >= lo && d[j] < hi) atomicAdd(&cnt[d[j]], 1);
    }
}

// ---------------- graph boundaries via binary search (batch is sorted) ----------------
__global__ void k_graph_bounds(const int* __restrict__ batch,
                               int* __restrict__ gstart, int* __restrict__ gcnt) {
    int g = threadIdx.x;  // 0..63
    int lo = 0, hi = N_NODES;
    while (lo < hi) { int mid = (lo + hi) >> 1; if (batch[mid] < g) lo = mid + 1; else hi = mid; }
    __shared__ int sh[N_GRAPHS + 1];
    sh[g] = lo;
    if (g == 0) sh[N_GRAPHS] = N_NODES;
    __syncthreads();
    gstart[g] = sh[g];
    gcnt[g]   = sh[g + 1] - sh[g];
}

// ---------------- fused: dinv + x padding ----------------
__global__ void k_dinv_xpad(const int* __restrict__ cnt, const float* __restrict__ x,
                            float* __restrict__ dinv, float4* __restrict__ xp) {
    int i = blockIdx.x * 256 + threadIdx.x;
    if (i < N_NODES) {
        dinv[i] = rsqrtf((float)cnt[i] + 1.0f);
        xp[i] = make_float4(x[i * 3 + 0], x[i * 3 + 1], x[i * 3 + 2], 0.f);
    }
}

// ---------------- exclusive scan of PADDED degree counts (CSR offsets) ----------------
__global__ void k_scanA(const int* __restrict__ cnt, int* __restrict__ out, int* __restrict__ bsum) {
    __shared__ int sh[256];
    int tid = threadIdx.x;
    int base = blockIdx.x * 1024 + tid * 4;
    int v[4]; int s = 0;
#pragma unroll
    for (int i = 0; i < 4; i++) {
        int idx = base + i;
        v[i] = (idx < N_NODES) ? ((cnt[idx] + 7) & ~7) : 0;
        s += v[i];
    }
    sh[tid] = s; __syncthreads();
    for (int off = 1; off < 256; off <<= 1) {
        int t = (tid >= off) ? sh[tid - off] : 0;
        __syncthreads();
        sh[tid] += t;
        __syncthreads();
    }
    int excl = sh[tid] - s;
    if (tid == 255) bsum[blockIdx.x] = sh[255];
#pragma unroll
    for (int i = 0; i < 4; i++) { int idx = base + i; if (idx < N_NODES) out[idx] = excl; excl += v[i]; }
}

__global__ void k_scanB(int* __restrict__ bsum, int nb) {
    __shared__ int sh[128];
    int tid = threadIdx.x;
    int v = (tid < nb) ? bsum[tid] : 0;
    sh[tid] = v; __syncthreads();
    for (int off = 1; off < 128; off <<= 1) {
        int t = (tid >= off) ? sh[tid - off] : 0;
        __syncthreads();
        sh[tid] += t;
        __syncthreads();
    }
    if (tid < nb) bsum[tid] = sh[tid] - v;  // exclusive
}

// finalize offsets + init cursor + zero records (src=0, coef=0.0) into padding slots
__global__ void k_scanC(int* __restrict__ off_arr, const int* __restrict__ bsum,
                        int* __restrict__ cursor, const int* __restrict__ cnt,
                        unsigned int* __restrict__ rec) {
    int i = blockIdx.x * 256 + threadIdx.x;
    if (i < N_NODES) {
        int v = off_arr[i] + bsum[i >> 10];
        off_arr[i] = v;
        cursor[i]  = v;
        int c  = cnt[i];
        int cp = (c + 7) & ~7;
        for (int p = v + c; p < v + cp; ++p) rec[p] = 0u;
        if (i == N_NODES - 1) off_arr[N_NODES] = v + cp;
    }
}

// ---------------- XCD-partitioned CSR fill, coef fused, 4B packed records ----------------
__global__ __launch_bounds__(256) void k_fill(const int* __restrict__ src, const int* __restrict__ dst,
                                              const float* __restrict__ dinv,
                                              int* __restrict__ cursor, unsigned int* __restrict__ rec) {
    int b = blockIdx.x;
    int r = b & (N_RANGES - 1);
    int lo = r * R_SIZE, hi = lo + R_SIZE;
    int e0 = (b >> 3) * CHUNK + threadIdx.x * 8;
    if (e0 >= N_EDGES) return;
    int4 da = *(const int4*)(dst + e0);
    int4 db = *(const int4*)(dst + e0 + 4);
    int d[8] = {da.x, da.y, da.z, da.w, db.x, db.y, db.z, db.w};
#pragma unroll
    for (int j = 0; j < 8; ++j) {
        if (d[j] >= lo && d[j] < hi) {
            int s = src[e0 + j];
            float c = dinv[s] * dinv[d[j]];
            int p = atomicAdd(&cursor[d[j]], 1);
            rec[p] = rec_pack(s, c);
        }
    }
}

// ---------------- weight prep: W[k][n] fp32 -> fp8 in MFMA-fragment-swizzled order ----------------
__global__ void k_wprep(const float* __restrict__ W, unsigned char* __restrict__ Wswz) {
    int n = blockIdx.x; int k = threadIdx.x;  // 256 x 256
    unsigned char v = f2fp8(W[k * HIDDEN + n]);
    int k0 = k >> 5, nt = n >> 4;
    int lane = (((k >> 3) & 3) << 4) | (n & 15);
    int j = k & 7;
    Wswz[(size_t)(((k0 * 16) + nt) * 64 + lane) * 8 + j] = v;
}

// ---------------- layer-1 reassociated: ax = Norm * x  (3 features) ----------------
__global__ void k_agg3(const float4* __restrict__ xp, const int* __restrict__ off,
                       const unsigned int* __restrict__ rec, const float* __restrict__ dinv,
                       float4* __restrict__ ax) {
    int i = blockIdx.x * 256 + threadIdx.x;
    if (i >= N_NODES) return;
    float di = dinv[i];
    float selfc = di * di;
    float4 xi = xp[i];
    float a0 = xi.x * selfc, a1 = xi.y * selfc, a2 = xi.z * selfc;
    int e = off[i], e1 = off[i + 1];
    for (; e < e1; e += 4) {
        uint4 rr = *(const uint4*)(rec + e);
        int s0 = rr.x & 0x1ffff, s1 = rr.y & 0x1ffff, s2 = rr.z & 0x1ffff, s3 = rr.w & 0x1ffff;
        float c0 = rec_coef(rr.x), c1 = rec_coef(rr.y), c2 = rec_coef(rr.z), c3 = rec_coef(rr.w);
        float4 x0 = xp[s0], x1 = xp[s1], x2 = xp[s2], x3 = xp[s3];
        a0 += c0 * x0.x + c1 * x1.x + c2 * x2.x + c3 * x3.x;
        a1 += c0 * x0.y + c1 * x1.y + c2 * x2.y + c3 * x3.y;
        a2 += c0 * x0.z + c1 * x1.z + c2 * x2.z + c3 * x3.z;
    }
    ax[i] = make_float4(a0, a1, a2, 0.f);
}

// h1 = leaky(ax @ W1 + b1), fp8 out (hA row-major, linear-read by GEMM)
__global__ void k_l1(const float4* __restrict__ ax, const float* __restrict__ W1,
                     const float* __restrict__ b1, unsigned char* __restrict__ out) {
    int node = blockIdx.x; int c = threadIdx.x;
    float4 a = ax[node];
    float v = a.x * W1[c] + a.y * W1[HIDDEN + c] + a.z * W1[2 * HIDDEN + c] + b1[c];
    v = v >= 0.f ? v : NEG_SLOPE * v;
    out[(size_t)node * HIDDEN + c] = f2fp8(v);
}

// ---------------- fp8 MFMA GEMM: whole W (64 KB fp8, pre-swizzled) in LDS, ONE barrier ----------------
__global__ __launch_bounds__(512, 2) void k_gemm_mfma(const unsigned char* __restrict__ A,
                                                      const unsigned char* __restrict__ Wswz,
                                                      unsigned char* __restrict__ C, int M) {
    __shared__ long Bs[8192];  // 64 KB
    int tid = threadIdx.x;
    {
        const float4* gsrc = (const float4*)Wswz;
        float4* ldst = (float4*)Bs;
#pragma unroll
        for (int i = 0; i < 8; ++i) ldst[tid + 512 * i] = gsrc[tid + 512 * i];
    }
    __syncthreads();
    int lane = tid & 63, wv = tid >> 6;
    int quad = lane >> 4, r = lane & 15;
    int nstrips = M >> 4;  // 6250
    for (int s = blockIdx.x * 8 + wv; s < nstrips; s += gridDim.x * 8) {
        int m0 = s * 16;
        const long* Ab = (const long*)(A + (size_t)(m0 + r) * HIDDEN) + quad;
        long af[8];
#pragma unroll
        for (int k0 = 0; k0 < 8; ++k0) af[k0] = Ab[k0 * 4];
#pragma unroll
        for (int half = 0; half < 2; ++half) {
            f32x4 acc[8];
#pragma unroll
            for (int i = 0; i < 8; i++) acc[i] = (f32x4){0.f, 0.f, 0.f, 0.f};
#pragma unroll
            for (int k0 = 0; k0 < 8; ++k0) {
#pragma unroll
                for (int nt = 0; nt < 8; ++nt) {
                    long b = Bs[(k0 * 16 + half * 8 + nt) * 64 + lane];
                    acc[nt] = __builtin_amdgcn_mfma_f32_16x16x32_fp8_fp8(af[k0], b, acc[nt], 0, 0, 0);
                }
            }
#pragma unroll
            for (int nt = 0; nt < 8; ++nt) {
#pragma unroll
                for (int i = 0; i < 4; ++i) {
                    int row = m0 + quad * 4 + i;
                    C[(size_t)row * HIDDEN + (half * 8 + nt) * 16 + r] = f2fp8(acc[nt][i]);
                }
            }
        }
    }
}

// ---------------- fused aggregation + self-loop + bias + leaky-relu ----------------
// one wave per node; h rows fp8 (256 B); 8 gathers in flight; 4B packed records
__global__ __launch_bounds__(256) void k_agg(const unsigned char* __restrict__ h,
                                             const float* __restrict__ bias,
                                             const int* __restrict__ off, const unsigned int* __restrict__ rec,
                                             const float* __restrict__ dinv,
                                             unsigned char* __restrict__ out) {
    int node = (blockIdx.x * 256 + threadIdx.x) >> 6;
    int lane = threadIdx.x & 63;
    if (node >= N_NODES) return;
    float di = dinv[node];
    float selfc = di * di;
    unsigned int hv = *(const unsigned int*)(h + (size_t)node * HIDDEN + lane * 4);
    f32x2 hlo = __builtin_amdgcn_cvt_pk_f32_fp8(hv, false);
    f32x2 hhi = __builtin_amdgcn_cvt_pk_f32_fp8(hv, true);
    float4 bv = ((const float4*)bias)[lane];
    float4 acc = make_float4(bv.x + hlo.x * selfc, bv.y + hlo.y * selfc,
                             bv.z + hhi.x * selfc, bv.w + hhi.y * selfc);
    int e = off[node], e1 = off[node + 1];
    for (; e < e1; e += 8) {
        uint4 ra = *(const uint4*)(rec + e);
        uint4 rb = *(const uint4*)(rec + e + 4);
        unsigned int w0 = *(const unsigned int*)(h + (size_t)(ra.x & 0x1ffff) * HIDDEN + lane * 4);
        unsigned int w1 = *(const unsigned int*)(h + (size_t)(ra.y & 0x1ffff) * HIDDEN + lane * 4);
        unsigned int w2 = *(const unsigned int*)(h + (size_t)(ra.z & 0x1ffff) * HIDDEN + lane * 4);
        unsigned int w3 = *(const unsigned int*)(h + (size_t)(ra.w & 0x1ffff) * HIDDEN + lane * 4);
        unsigned int w4 = *(const unsigned int*)(h + (size_t)(rb.x & 0x1ffff) * HIDDEN + lane * 4);
        unsigned int w5 = *(const unsigned int*)(h + (size_t)(rb.y & 0x1ffff) * HIDDEN + lane * 4);
        unsigned int w6 = *(const unsigned int*)(h + (size_t)(rb.z & 0x1ffff) * HIDDEN + lane * 4);
        unsigned int w7 = *(const unsigned int*)(h + (size_t)(rb.w & 0x1ffff) * HIDDEN + lane * 4);
        float c0 = rec_coef(ra.x), c1 = rec_coef(ra.y), c2 = rec_coef(ra.z), c3 = rec_coef(ra.w);
        float c4 = rec_coef(rb.x), c5 = rec_coef(rb.y), c6 = rec_coef(rb.z), c7 = rec_coef(rb.w);
        f32x2 l0 = __builtin_amdgcn_cvt_pk_f32_fp8(w0, false), g0 = __builtin_amdgcn_cvt_pk_f32_fp8(w0, true);
        f32x2 l1 = __builtin_amdgcn_cvt_pk_f32_fp8(w1, false), g1 = __builtin_amdgcn_cvt_pk_f32_fp8(w1, true);
        f32x2 l2 = __builtin_amdgcn_cvt_pk_f32_fp8(w2, false), g2 = __builtin_amdgcn_cvt_pk_f32_fp8(w2, true);
        f32x2 l3 = __builtin_amdgcn_cvt_pk_f32_fp8(w3, false), g3 = __builtin_amdgcn_cvt_pk_f32_fp8(w3, true);
        f32x2 l4 = __builtin_amdgcn_cvt_pk_f32_fp8(w4, false), g4 = __builtin_amdgcn_cvt_pk_f32_fp8(w4, true);
        f32x2 l5 = __builtin_amdgcn_cvt_pk_f32_fp8(w5, false), g5 = __builtin_amdgcn_cvt_pk_f32_fp8(w5, true);
        f32x2 l6 = __builtin_amdgcn_cvt_pk_f32_fp8(w6, false), g6 = __builtin_amdgcn_cvt_pk_f32_fp8(w6, true);
        f32x2 l7 = __builtin_amdgcn_cvt_pk_f32_fp8(w7, false), g7 = __builtin_amdgcn_cvt_pk_f32_fp8(w7, true);
        acc.x += c0 * l0.x + c1 * l1.x + c2 * l2.x + c3 * l3.x
               + c4 * l4.x + c5 * l5.x + c6 * l6.x + c7 * l7.x;
        acc.y += c0 * l0.y + c1 * l1.y + c2 * l2.y + c3 * l3.y
               + c4 * l4.y + c5 * l5.y + c6 * l6.y + c7 * l7.y;
        acc.z += c0 * g0.x + c1 * g1.x + c2 * g2.x + c3 * g3.x
               + c4 * g4.x + c5 * g5.x + c6 * g6.x + c7 * g7.x;
        acc.w += c0 * g0.y + c1 * g1.y + c2 * g2.y + c3 * g3.y
               + c4 * g4.y + c5 * g5.y + c6 * g6.y + c7 * g7.y;
    }
    acc.x = acc.x >= 0.f ? acc.x : NEG_SLOPE * acc.x;
    acc.y = acc.y >= 0.f ? acc.y : NEG_SLOPE * acc.y;
    acc.z = acc.z >= 0.f ? acc.z : NEG_SLOPE * acc.z;
    acc.w = acc.w >= 0.f ? acc.w : NEG_SLOPE * acc.w;
    unsigned int pk = __builtin_amdgcn_cvt_pk_fp8_f32(acc.x, acc.y, 0, false);
    pk = __builtin_amdgcn_cvt_pk_fp8_f32(acc.z, acc.w, pk, true);
    *(unsigned int*)(out + (size_t)node * HIDDEN + lane * 4) = pk;
}

// ---------------- global mean pool (partial sums + atomics), fp8 input ----------------
__global__ void k_pool(const unsigned char* __restrict__ h, const int* __restrict__ gstart,
                       const int* __restrict__ gcnt, float* __restrict__ pooled) {
    int g = blockIdx.x, chunk = blockIdx.y, t = threadIdx.x;
    int s = gstart[g], c = gcnt[g];
    int i0 = s + (int)(((long long)c * chunk) / 16);
    int i1 = s + (int)(((long long)c * (chunk + 1)) / 16);
    float acc = 0.f;
    for (int i = i0; i < i1; ++i) {
        f32x2 v = __builtin_amdgcn_cvt_pk_f32_fp8((unsigned int)h[(size_t)i * HIDDEN + t], false);
        acc += v.x;
    }
    atomicAdd(&pooled[g * HIDDEN + t], acc);
}

// ---------------- classifier head + softmax (one wave per graph) ----------------
__global__ void k_head(const float* __restrict__ pooled, const int* __restrict__ gcnt,
                       const float* __restrict__ Wc, const float* __restrict__ bc,
                       float* __restrict__ out) {
    int g = blockIdx.x; int l = threadIdx.x;  // 64 threads
    float inv = 1.0f / fmaxf((float)gcnt[g], 1.0f);
    float p[4];
#pragma unroll
    for (int i = 0; i < 4; i++) p[i] = pooled[g * HIDDEN + l + i * 64] * inv;
    __shared__ float logits[N_CLASSES];
#pragma unroll
    for (int j = 0; j < N_CLASSES; j++) {
        float s = 0.f;
#pragma unroll
        for (int i = 0; i < 4; i++) s += p[i] * Wc[(l + i * 64) * N_CLASSES + j];
        for (int o = 32; o > 0; o >>= 1) s += __shfl_down(s, o, 64);
        if (l == 0) logits[j] = s + bc[j];
    }
    __syncthreads();
    if (l == 0) {
        float m = logits[0];
        for (int j = 1; j < N_CLASSES; j++) m = fmaxf(m, logits[j]);
        float e[N_CLASSES]; float sum = 0.f;
        for (int j = 0; j < N_CLASSES; j++) { e[j] = expf(logits[j] - m); sum += e[j]; }
        for (int j = 0; j < N_CLASSES; j++) out[g * N_CLASSES + j] = e[j] / sum;
    }
}

extern "C" void kernel_launch(void* const* d_in, const int* in_sizes, int n_in,
                              void* d_out, int out_size, void* d_ws, size_t ws_size,
                              hipStream_t stream) {
    const float* x     = (const float*)d_in[0];
    const int*   edge  = (const int*)d_in[1];
    const int*   batch = (const int*)d_in[2];
    const float* W1 = (const float*)d_in[3];
    const float* b1 = (const float*)d_in[4];
    const float* W2 = (const float*)d_in[5];
    const float* b2 = (const float*)d_in[6];
    const float* W3 = (const float*)d_in[7];
    const float* b3 = (const float*)d_in[8];
    const float* Wc = (const float*)d_in[9];
    const float* bc = (const float*)d_in[10];
    float* out = (float*)d_out;
    const int* srcp = edge;
    const int* dstp = edge + N_EDGES;

    char* ws = (char*)d_ws;
    size_t off = 0;
    auto alloc = [&](size_t bytes) -> char* {
        char* p = ws + off;
        off += (bytes + 255) & ~(size_t)255;
        return p;
    };
    unsigned char* hA   = (unsigned char*)alloc((size_t)N_NODES * HIDDEN);  // row-major fp8 (GEMM in)
    unsigned char* hB   = (unsigned char*)alloc((size_t)N_NODES * HIDDEN);  // row-major fp8 (gathered)
    unsigned char* Wz2  = (unsigned char*)alloc((size_t)HIDDEN * HIDDEN);
    unsigned char* Wz3  = (unsigned char*)alloc((size_t)HIDDEN * HIDDEN);
    int*   deg_cnt  = (int*)alloc((size_t)N_NODES * 4);
    float* dinv     = (float*)alloc((size_t)N_NODES * 4);
    int*   csr_off  = (int*)alloc((size_t)(N_NODES + 1) * 4);
    int*   cursor   = (int*)alloc((size_t)N_NODES * 4);
    unsigned int* csr_rec = (unsigned int*)alloc((size_t)E_PAD * 4);
    float4* ax      = (float4*)alloc((size_t)N_NODES * 16);
    float4* xp      = (float4*)alloc((size_t)N_NODES * 16);
    int*   gcnt     = (int*)alloc((size_t)N_GRAPHS * 4);
    int*   gstart   = (int*)alloc((size_t)N_GRAPHS * 4);
    float* pooled   = (float*)alloc((size_t)N_GRAPHS * HIDDEN * 4);
    int*   bsum     = (int*)alloc(128 * 4);

    hipMemsetAsync(deg_cnt, 0, (size_t)N_NODES * 4, stream);
    hipMemsetAsync(pooled, 0, (size_t)N_GRAPHS * HIDDEN * 4, stream);

    int nb  = (N_NODES + 255) / 256;
    int sblocks = (N_NODES + 1023) / 1024;  // 98
    int fillb = N_RANGES * ((N_EDGES + CHUNK - 1) / CHUNK);  // 8 x 782

    k_deg_hist<<<fillb, 256, 0, stream>>>(dstp, deg_cnt);
    k_graph_bounds<<<1, 64, 0, stream>>>(batch, gstart, gcnt);
    k_dinv_xpad<<<nb, 256, 0, stream>>>(deg_cnt, x, dinv, xp);
    k_scanA<<<sblocks, 256, 0, stream>>>(deg_cnt, csr_off, bsum);
    k_scanB<<<1, 128, 0, stream>>>(bsum, sblocks);
    k_scanC<<<nb, 256, 0, stream>>>(csr_off, bsum, cursor, deg_cnt, csr_rec);
    k_fill<<<fillb, 256, 0, stream>>>(srcp, dstp, dinv, cursor, csr_rec);
    k_wprep<<<HIDDEN, HIDDEN, 0, stream>>>(W2, Wz2);
    k_wprep<<<HIDDEN, HIDDEN, 0, stream>>>(W3, Wz3);

    // layer 1 (reassociated): ax = Norm*x; h1 = leaky(ax @ W1 + b1) -> hA (fp8)
    k_agg3<<<nb, 256, 0, stream>>>(xp, csr_off, csr_rec, dinv, ax);
    k_l1<<<N_NODES, 256, 0, stream>>>(ax, W1, b1, hA);

    int aggb = (N_NODES + 3) / 4;
    // layer 2
    k_gemm_mfma<<<GEMM_BLOCKS, 512, 0, stream>>>(hA, Wz2, hB, N_NODES);
    k_agg<<<aggb, 256, 0, stream>>>(hB, b2, csr_off, csr_rec, dinv, hA);
    // layer 3
    k_gemm_mfma<<<GEMM_BLOCKS, 512, 0, stream>>>(hA, Wz3, hB, N_NODES);
    k_agg<<<aggb, 256, 0, stream>>>(hB, b3, csr_off, csr_rec, dinv, hA);
    // pool + head
    dim3 pg(N_GRAPHS, 16);
    k_pool<<<pg, 256, 0, stream>>>(hA, gstart, gcnt, pooled);
    k_head<<<N_GRAPHS, 64, 0, stream>>>(pooled, gcnt, Wc, bc, out);
}